// Round 11
// baseline (299.218 us; speedup 1.0000x reference)
//
#include <hip/hip_runtime.h>
#include <hip/hip_bf16.h>

#define N_NODES_C 50000
#define N_EDGES_C 800000
#define IN_DIM_C 64
#define HID_C 256
#define EDGE_DIM_C 6
#define NEG_SLOPE_C 0.2f

typedef short short8 __attribute__((ext_vector_type(8)));
typedef float f32x4 __attribute__((ext_vector_type(4)));

static __device__ __forceinline__ float b2f(unsigned short u) {
    union { unsigned int i; float f; } x;
    x.i = ((unsigned int)u) << 16;
    return x.f;
}
static __device__ __forceinline__ unsigned short f2b(float f) {
    union { __hip_bfloat16 h; unsigned short u; } x;
    x.h = __float2bfloat16(f);
    return x.u;
}

// ---- shared aggregation core: one halfwave aggregates one node's 8 columns/lane ----
static __device__ __forceinline__ float aggr_node(int off0, int deg, float adi,
                                                  const int* __restrict__ ssrc,
                                                  const float* __restrict__ sae,
                                                  const float* __restrict__ asrc,
                                                  const unsigned short* __restrict__ H,
                                                  int l, float* acc) {
    int sidx0 = 0, sidx1 = 0;
    float w0 = 0.f, w1 = 0.f;
    if (l < deg) {
        sidx0 = ssrc[off0 + l];
        float a = asrc[sidx0] + adi + sae[off0 + l];
        a = (a > 0.f) ? a : NEG_SLOPE_C * a;
        w0 = __expf(a);
    }
    if (32 + l < deg) {
        sidx1 = ssrc[off0 + 32 + l];
        float a = asrc[sidx1] + adi + sae[off0 + 32 + l];
        a = (a > 0.f) ? a : NEG_SLOPE_C * a;
        w1 = __expf(a);
    }
    float s = w0 + w1;
    for (int j = 64 + l; j < deg; j += 32) {  // cold tail
        int si = ssrc[off0 + j];
        float a = asrc[si] + adi + sae[off0 + j];
        a = (a > 0.f) ? a : NEG_SLOPE_C * a;
        s += __expf(a);
    }
#pragma unroll
    for (int o = 16; o > 0; o >>= 1) s += __shfl_xor(s, o, 32);
    float inv = 1.0f / (s + 1e-16f);

    int c8 = l * 8;
#pragma unroll
    for (int q = 0; q < 8; ++q) acc[q] = 0.f;

    auto fetch = [&](int j, int& si, float& wv) {
        if (j < 32) {
            si = __shfl(sidx0, j, 32);
            wv = __shfl(w0, j, 32);
        } else if (j < 64) {
            si = __shfl(sidx1, j - 32, 32);
            wv = __shfl(w1, j - 32, 32);
        } else {
            si = ssrc[off0 + j];
            float a = asrc[si] + adi + sae[off0 + j];
            a = (a > 0.f) ? a : NEG_SLOPE_C * a;
            wv = __expf(a);
        }
    };

    int j = 0;
    for (; j + 7 < deg; j += 8) {
        int ii[8];
        float uu[8];
#pragma unroll
        for (int q = 0; q < 8; ++q) fetch(j + q, ii[q], uu[q]);
        short8 h[8];
#pragma unroll
        for (int q = 0; q < 8; ++q) h[q] = *(const short8*)&H[(long)ii[q] * HID_C + c8];
#pragma unroll
        for (int t = 0; t < 8; ++t)
#pragma unroll
            for (int q = 0; q < 8; ++q) acc[q] += uu[t] * b2f((unsigned short)h[t][q]);
    }
    for (; j + 3 < deg; j += 4) {
        int ii[4];
        float uu[4];
#pragma unroll
        for (int q = 0; q < 4; ++q) fetch(j + q, ii[q], uu[q]);
        short8 h[4];
#pragma unroll
        for (int q = 0; q < 4; ++q) h[q] = *(const short8*)&H[(long)ii[q] * HID_C + c8];
#pragma unroll
        for (int t = 0; t < 4; ++t)
#pragma unroll
            for (int q = 0; q < 8; ++q) acc[q] += uu[t] * b2f((unsigned short)h[t][q]);
    }
    for (; j < deg; ++j) {
        int i0;
        float u0;
        fetch(j, i0, u0);
        short8 h0 = *(const short8*)&H[(long)i0 * HID_C + c8];
#pragma unroll
        for (int q = 0; q < 8; ++q) acc[q] += u0 * b2f((unsigned short)h0[q]);
    }
    return inv;
}

// ---------------- prep: W transposes + v12 (block 255) + zero deg ----------------
__global__ void k_prep(const float* __restrict__ W1, const float* __restrict__ W2,
                       unsigned short* __restrict__ W1t, unsigned short* __restrict__ W2t,
                       const float* __restrict__ We1, const float* __restrict__ atte1,
                       const float* __restrict__ We2, const float* __restrict__ atte2,
                       float* __restrict__ v, int* __restrict__ deg) {
    int tid = threadIdx.x;
    int i = blockIdx.x * blockDim.x + tid;
    if (i < N_NODES_C) deg[i] = 0;
    if (i < IN_DIM_C * HID_C) {
        int k = i >> 8, n = i & 255;
        W1t[n * IN_DIM_C + k] = f2b(W1[i]);
    }
    if (i < HID_C * HID_C) {
        int k = i >> 8, n = i & 255;
        W2t[n * HID_C + k] = f2b(W2[i]);
    }
    if (blockIdx.x == 255) {
        __shared__ float red[256];
        for (int layer = 0; layer < 2; ++layer) {
            const float* We = layer ? We2 : We1;
            const float* ae = layer ? atte2 : atte1;
            for (int k = 0; k < EDGE_DIM_C; ++k) {
                red[tid] = We[k * HID_C + tid] * ae[tid];
                __syncthreads();
                for (int s = 128; s > 0; s >>= 1) {
                    if (tid < s) red[tid] += red[tid + s];
                    __syncthreads();
                }
                if (tid == 0) v[layer * 8 + k] = red[0];
                __syncthreads();
            }
        }
    }
}

#define GEMM1_BLOCKS 782  // ceil(50000/64)

// ---------------- fused: GEMM1 (blocks < 782) + edge-pre (blocks >= 782) ----------
__global__ __launch_bounds__(256) void k_pre_gemm1(
    const float* __restrict__ X, const unsigned short* __restrict__ Wt,
    unsigned short* __restrict__ H, const float* __restrict__ att_s,
    const float* __restrict__ att_d, float* __restrict__ asrc,
    float* __restrict__ adst,
    const int* __restrict__ dst, const float* __restrict__ eattr,
    const float* __restrict__ v, int* __restrict__ deg,
    float* __restrict__ ae1, float* __restrict__ ae2) {
    __shared__ unsigned short As[64 * 64];
    __shared__ unsigned short Bs[256 * 64];
    __shared__ float ds[4][64];
    __shared__ float dd[4][64];
    int tid = threadIdx.x;

    if (blockIdx.x >= GEMM1_BLOCKS) {
        int e = (blockIdx.x - GEMM1_BLOCKS) * 256 + tid;
        if (e < N_EDGES_C) {
            atomicAdd(&deg[dst[e]], 1);
            float a1 = 0.f, a2 = 0.f;
#pragma unroll
            for (int k = 0; k < EDGE_DIM_C; ++k) {
                float ea = eattr[e * EDGE_DIM_C + k];
                a1 += ea * v[k];
                a2 += ea * v[8 + k];
            }
            ae1[e] = a1;
            ae2[e] = a2;
        }
        return;
    }

    int w = tid >> 6, l = tid & 63;
    int lr = l & 15, lg = l >> 4;
    long mbase = (long)blockIdx.x * 64;

    float asv[4], adv[4];
#pragma unroll
    for (int ni = 0; ni < 4; ++ni) {
        int col = w * 64 + ni * 16 + lr;
        asv[ni] = att_s[col];
        adv[ni] = att_d[col];
    }

    f32x4 acc[4][4];
#pragma unroll
    for (int mi = 0; mi < 4; ++mi)
#pragma unroll
        for (int ni = 0; ni < 4; ++ni) acc[mi][ni] = (f32x4){0.f, 0.f, 0.f, 0.f};

    {
#pragma unroll
        for (int p = 0; p < 2; ++p) {
            int r = p * 32 + (tid >> 3);
            int c8 = tid & 7;
            long row = mbase + r;
            short8 val = {0, 0, 0, 0, 0, 0, 0, 0};
            if (row < N_NODES_C) {
                const f32x4* p4 = (const f32x4*)&X[row * IN_DIM_C + c8 * 8];
                f32x4 a0 = p4[0], a1 = p4[1];
#pragma unroll
                for (int q = 0; q < 4; ++q) val[q] = (short)f2b(a0[q]);
#pragma unroll
                for (int q = 0; q < 4; ++q) val[4 + q] = (short)f2b(a1[q]);
            }
            *(short8*)&As[r * 64 + ((c8 ^ (r & 7)) * 8)] = val;
        }
        int n = tid;
#pragma unroll
        for (int c8 = 0; c8 < 8; ++c8) {
            *(short8*)&Bs[n * 64 + ((c8 ^ (n & 7)) * 8)] =
                *(const short8*)&Wt[(long)n * IN_DIM_C + c8 * 8];
        }
        __syncthreads();
#pragma unroll
        for (int kk = 0; kk < 2; ++kk) {
            int cblk = kk * 4 + lg;
            short8 a[4], b[4];
#pragma unroll
            for (int mi = 0; mi < 4; ++mi) {
                int R = mi * 16 + lr;
                a[mi] = *(const short8*)&As[R * 64 + ((cblk ^ (R & 7)) * 8)];
            }
#pragma unroll
            for (int ni = 0; ni < 4; ++ni) {
                int Nr = w * 64 + ni * 16 + lr;
                b[ni] = *(const short8*)&Bs[Nr * 64 + ((cblk ^ (Nr & 7)) * 8)];
            }
#pragma unroll
            for (int mi = 0; mi < 4; ++mi)
#pragma unroll
                for (int ni = 0; ni < 4; ++ni)
                    acc[mi][ni] = __builtin_amdgcn_mfma_f32_16x16x32_bf16(a[mi], b[ni],
                                                                          acc[mi][ni], 0, 0, 0);
        }
        __syncthreads();
    }

#pragma unroll
    for (int mi = 0; mi < 4; ++mi) {
#pragma unroll
        for (int r = 0; r < 4; ++r) {
            int rowl = mi * 16 + lg * 4 + r;
            long row = mbase + rowl;
            float ps = 0.f, pd = 0.f;
#pragma unroll
            for (int ni = 0; ni < 4; ++ni) {
                float h = acc[mi][ni][r];
                ps += h * asv[ni];
                pd += h * adv[ni];
            }
#pragma unroll
            for (int o = 1; o < 16; o <<= 1) {
                ps += __shfl_xor(ps, o, 16);
                pd += __shfl_xor(pd, o, 16);
            }
            if (lr == 0) {
                ds[w][rowl] = ps;
                dd[w][rowl] = pd;
            }
            if (row < N_NODES_C) {
#pragma unroll
                for (int ni = 0; ni < 4; ++ni) {
                    H[row * HID_C + w * 64 + ni * 16 + lr] = f2b(acc[mi][ni][r]);
                }
            }
        }
    }
    __syncthreads();
    if (tid < 64) {
        long row = mbase + tid;
        if (row < N_NODES_C) {
            asrc[row] = ds[0][tid] + ds[1][tid] + ds[2][tid] + ds[3][tid];
            adst[row] = dd[0][tid] + dd[1][tid] + dd[2][tid] + dd[3][tid];
        }
    }
}

// ---------------- two-level scan ----------------
__global__ void k_scan1(const int* __restrict__ deg, int* __restrict__ offs,
                        int* __restrict__ bsum) {
    __shared__ int tmp[256];
    int b = blockIdx.x, tid = threadIdx.x;
    int i = b * 256 + tid;
    int v = (i < N_NODES_C) ? deg[i] : 0;
    tmp[tid] = v;
    __syncthreads();
    for (int d = 1; d < 256; d <<= 1) {
        int t = (tid >= d) ? tmp[tid - d] : 0;
        __syncthreads();
        tmp[tid] += t;
        __syncthreads();
    }
    if (i < N_NODES_C) offs[i] = tmp[tid] - v;
    if (tid == 255) bsum[b] = tmp[255];
}
__global__ void k_scan2(const int* __restrict__ bsum, int* __restrict__ boff, int nb) {
    __shared__ int tmp[256];
    int tid = threadIdx.x;
    int v = (tid < nb) ? bsum[tid] : 0;
    tmp[tid] = v;
    __syncthreads();
    for (int d = 1; d < 256; d <<= 1) {
        int t = (tid >= d) ? tmp[tid - d] : 0;
        __syncthreads();
        tmp[tid] += t;
        __syncthreads();
    }
    if (tid < nb) boff[tid] = tmp[tid] - v;
}
__global__ void k_scan3(int* __restrict__ offs, const int* __restrict__ boff,
                        int* __restrict__ cur) {
    int b = blockIdx.x, tid = threadIdx.x;
    int i = b * 256 + tid;
    if (i < N_NODES_C) {
        int o = offs[i] + boff[b];
        offs[i] = o;
        cur[i] = o;
    }
    if (i == 0) offs[N_NODES_C] = N_EDGES_C;
}

// ---------------- perm build ----------------
__global__ void k_perm(const int* __restrict__ dst, int* __restrict__ cur,
                       int* __restrict__ perm) {
    int e = blockIdx.x * blockDim.x + threadIdx.x;
    if (e >= N_EDGES_C) return;
    int pos = atomicAdd(&cur[dst[e]], 1);
    perm[pos] = e;
}

// ---------------- CSR materialization ----------------
__global__ void k_gather(const int* __restrict__ perm, const int* __restrict__ src,
                         const float* __restrict__ ae1, const float* __restrict__ ae2,
                         int* __restrict__ ssrc, float* __restrict__ sae1,
                         float* __restrict__ sae2) {
    int p = blockIdx.x * blockDim.x + threadIdx.x;
    if (p >= N_EDGES_C) return;
    int e = perm[p];
    ssrc[p] = src[e];
    sae1[p] = ae1[e];
    sae2[p] = ae2[e];
}

// ---------------- aggregation: halfwave per node; mode1 = bf16+relu, mode0 = f32 ------
__global__ __launch_bounds__(256) void k_aggr2(const int* __restrict__ offs,
                                               const int* __restrict__ ssrc,
                                               const float* __restrict__ sae,
                                               const float* __restrict__ asrc,
                                               const float* __restrict__ adst,
                                               const unsigned short* __restrict__ H,
                                               const float* __restrict__ bias,
                                               void* __restrict__ outp, int mode) {
    int tid = threadIdx.x;
    int hw = tid >> 5;
    int l = tid & 31;
    int node = blockIdx.x * 8 + hw;
    int off0 = offs[node];
    int deg = offs[node + 1] - off0;
    float adi = adst[node];
    float acc[8];
    float inv = aggr_node(off0, deg, adi, ssrc, sae, asrc, H, l, acc);
    int c8 = l * 8;
    const f32x4* b4 = (const f32x4*)&bias[c8];
    f32x4 bv0 = b4[0], bv1 = b4[1];
    if (mode == 1) {
        unsigned short* o16 = (unsigned short*)outp;
        short8 r;
#pragma unroll
        for (int q = 0; q < 4; ++q)
            r[q] = (short)f2b(fmaxf(acc[q] * inv + bv0[q], 0.f));
#pragma unroll
        for (int q = 0; q < 4; ++q)
            r[4 + q] = (short)f2b(fmaxf(acc[4 + q] * inv + bv1[q], 0.f));
        *(short8*)&o16[(long)node * HID_C + c8] = r;
    } else {
        float* o32 = (float*)outp;
        f32x4 r0, r1;
#pragma unroll
        for (int q = 0; q < 4; ++q) r0[q] = acc[q] * inv + bv0[q];
#pragma unroll
        for (int q = 0; q < 4; ++q) r1[q] = acc[4 + q] * inv + bv1[q];
        *(f32x4*)&o32[(long)node * HID_C + c8] = r0;
        *(f32x4*)&o32[(long)node * HID_C + c8 + 4] = r1;
    }
}

// ---------------- GEMM2: A staged g1->LDS (swizzled), B direct from L2, fused dots ----
__global__ __launch_bounds__(256) void k_gemm2(
    const unsigned short* __restrict__ G, const unsigned short* __restrict__ Wt,
    unsigned short* __restrict__ H2, const float* __restrict__ att_s,
    const float* __restrict__ att_d, float* __restrict__ asrc2,
    float* __restrict__ adst2) {
    __shared__ unsigned short As[64 * 256];  // 32 KB, swizzled per 64-elem chunk
    __shared__ float ds[4][64];
    __shared__ float dd[4][64];
    int tid = threadIdx.x;
    long mbase = (long)blockIdx.x * 64;

    // stage A: 8 passes x 8 halfwaves; lane l loads 16B of row rowl
    int hw = tid >> 5, l = tid & 31;
#pragma unroll
    for (int p = 0; p < 8; ++p) {
        int rowl = p * 8 + hw;
        long row = mbase + rowl;
        short8 val = {0, 0, 0, 0, 0, 0, 0, 0};
        if (row < N_NODES_C) val = *(const short8*)&G[row * HID_C + l * 8];
        *(short8*)&As[rowl * 256 + (l >> 3) * 64 + (((l & 7) ^ (rowl & 7)) * 8)] = val;
    }
    __syncthreads();

    int w = tid >> 6, l64 = tid & 63;
    int lr = l64 & 15, lg = l64 >> 4;

    float asv[4], adv[4];
#pragma unroll
    for (int ni = 0; ni < 4; ++ni) {
        int col = w * 64 + ni * 16 + lr;
        asv[ni] = att_s[col];
        adv[ni] = att_d[col];
    }

    f32x4 acc[4][4];
#pragma unroll
    for (int mi = 0; mi < 4; ++mi)
#pragma unroll
        for (int ni = 0; ni < 4; ++ni) acc[mi][ni] = (f32x4){0.f, 0.f, 0.f, 0.f};

#pragma unroll
    for (int k0 = 0; k0 < HID_C; k0 += 64) {
#pragma unroll
        for (int kk = 0; kk < 2; ++kk) {
            int cblk = kk * 4 + lg;
            short8 a[4], b[4];
#pragma unroll
            for (int mi = 0; mi < 4; ++mi) {
                int R = mi * 16 + lr;
                a[mi] = *(const short8*)&As[R * 256 + k0 + ((cblk ^ (R & 7)) * 8)];
            }
#pragma unroll
            for (int ni = 0; ni < 4; ++ni) {
                int Nr = w * 64 + ni * 16 + lr;
                b[ni] = *(const short8*)&Wt[(long)Nr * HID_C + k0 + cblk * 8];
            }
#pragma unroll
            for (int mi = 0; mi < 4; ++mi)
#pragma unroll
                for (int ni = 0; ni < 4; ++ni)
                    acc[mi][ni] = __builtin_amdgcn_mfma_f32_16x16x32_bf16(a[mi], b[ni],
                                                                          acc[mi][ni], 0, 0, 0);
        }
    }

#pragma unroll
    for (int mi = 0; mi < 4; ++mi) {
#pragma unroll
        for (int r = 0; r < 4; ++r) {
            int rowl = mi * 16 + lg * 4 + r;
            long row = mbase + rowl;
            float ps = 0.f, pd = 0.f;
#pragma unroll
            for (int ni = 0; ni < 4; ++ni) {
                float h = acc[mi][ni][r];
                ps += h * asv[ni];
                pd += h * adv[ni];
            }
#pragma unroll
            for (int o = 1; o < 16; o <<= 1) {
                ps += __shfl_xor(ps, o, 16);
                pd += __shfl_xor(pd, o, 16);
            }
            if (lr == 0) {
                ds[w][rowl] = ps;
                dd[w][rowl] = pd;
            }
            if (row < N_NODES_C) {
#pragma unroll
                for (int ni = 0; ni < 4; ++ni) {
                    H2[row * HID_C + w * 64 + ni * 16 + lr] = f2b(acc[mi][ni][r]);
                }
            }
        }
    }
    __syncthreads();
    if (tid < 64) {
        long row = mbase + tid;
        if (row < N_NODES_C) {
            asrc2[row] = ds[0][tid] + ds[1][tid] + ds[2][tid] + ds[3][tid];
            adst2[row] = dd[0][tid] + dd[1][tid] + dd[2][tid] + dd[3][tid];
        }
    }
}

extern "C" void kernel_launch(void* const* d_in, const int* in_sizes, int n_in,
                              void* d_out, int out_size, void* d_ws, size_t ws_size,
                              hipStream_t stream) {
    const float* x     = (const float*)d_in[0];
    const int*   ei    = (const int*)d_in[1];     // [2, E]: row0=src, row1=dst
    const float* eattr = (const float*)d_in[2];
    const float* W1    = (const float*)d_in[3];
    const float* atts1 = (const float*)d_in[4];
    const float* attd1 = (const float*)d_in[5];
    const float* We1   = (const float*)d_in[6];
    const float* atte1 = (const float*)d_in[7];
    const float* b1    = (const float*)d_in[8];
    const float* W2    = (const float*)d_in[9];
    const float* atts2 = (const float*)d_in[10];
    const float* attd2 = (const float*)d_in[11];
    const float* We2   = (const float*)d_in[12];
    const float* atte2 = (const float*)d_in[13];
    const float* b2    = (const float*)d_in[14];
    float* out = (float*)d_out;

    char* ws = (char*)d_ws;
    size_t off = 0;
    auto alloc = [&](size_t bytes) -> void* {
        void* p = ws + off;
        off = (off + bytes + 255) & ~(size_t)255;
        return p;
    };
    int*   deg   = (int*)alloc((size_t)N_NODES_C * 4);
    int*   offs  = (int*)alloc(((size_t)N_NODES_C + 1) * 4);
    int*   cur   = (int*)alloc((size_t)N_NODES_C * 4);
    int*   perm  = (int*)alloc((size_t)N_EDGES_C * 4);
    int*   ssrc  = (int*)alloc((size_t)N_EDGES_C * 4);
    float* ae1   = (float*)alloc((size_t)N_EDGES_C * 4);
    float* ae2   = (float*)alloc((size_t)N_EDGES_C * 4);
    float* sae1  = (float*)alloc((size_t)N_EDGES_C * 4);
    float* sae2  = (float*)alloc((size_t)N_EDGES_C * 4);
    float* asrc  = (float*)alloc((size_t)N_NODES_C * 4);
    float* adst  = (float*)alloc((size_t)N_NODES_C * 4);
    float* asrc2 = (float*)alloc((size_t)N_NODES_C * 4);
    float* adst2 = (float*)alloc((size_t)N_NODES_C * 4);
    float* v     = (float*)alloc(64);
    int*   bsum  = (int*)alloc(256 * 4);
    int*   boff  = (int*)alloc(257 * 4);
    unsigned short* W1t = (unsigned short*)alloc((size_t)HID_C * IN_DIM_C * 2);
    unsigned short* W2t = (unsigned short*)alloc((size_t)HID_C * HID_C * 2);
    unsigned short* h1  = (unsigned short*)alloc((size_t)N_NODES_C * HID_C * 2);
    unsigned short* g1  = (unsigned short*)alloc((size_t)N_NODES_C * HID_C * 2);
    unsigned short* h2  = h1;  // layer-2 features overwrite h1 (h1 dead after aggr1)

    const int* src = ei;
    const int* dst = ei + N_EDGES_C;
    int nb = (N_NODES_C + 255) / 256;  // 196
    int pre_blocks = (N_EDGES_C + 255) / 256;  // 3125
    int gemm_grid = (N_NODES_C + 63) / 64;     // 782 == GEMM1_BLOCKS

    k_prep<<<256, 256, 0, stream>>>(W1, W2, W1t, W2t, We1, atte1, We2, atte2, v, deg);
    k_pre_gemm1<<<GEMM1_BLOCKS + pre_blocks, 256, 0, stream>>>(
        x, W1t, h1, atts1, attd1, asrc, adst, dst, eattr, v, deg, ae1, ae2);
    k_scan1<<<nb, 256, 0, stream>>>(deg, offs, bsum);
    k_scan2<<<1, 256, 0, stream>>>(bsum, boff, nb);
    k_scan3<<<nb, 256, 0, stream>>>(offs, boff, cur);
    k_perm<<<pre_blocks, 256, 0, stream>>>(dst, cur, perm);
    k_gather<<<pre_blocks, 256, 0, stream>>>(perm, src, ae1, ae2, ssrc, sae1, sae2);

    // layer 1 aggregation -> bf16 g1
    k_aggr2<<<N_NODES_C / 8, 256, 0, stream>>>(offs, ssrc, sae1, asrc, adst, h1, b1, g1, 1);
    // layer 2 GEMM (g1 -> h2) + fused dots
    k_gemm2<<<gemm_grid, 256, 0, stream>>>(g1, W2t, h2, atts2, attd2, asrc2, adst2);
    // layer 2 aggregation -> f32 out
    k_aggr2<<<N_NODES_C / 8, 256, 0, stream>>>(offs, ssrc, sae2, asrc2, adst2, h2, b2, out, 0);
}

// Round 12
// 249.056 us; speedup vs baseline: 1.2014x; 1.2014x over previous
//
#include <hip/hip_runtime.h>
#include <hip/hip_bf16.h>

#define N_NODES_C 50000
#define N_EDGES_C 800000
#define IN_DIM_C 64
#define HID_C 256
#define EDGE_DIM_C 6
#define NEG_SLOPE_C 0.2f

typedef short short8 __attribute__((ext_vector_type(8)));
typedef float f32x4 __attribute__((ext_vector_type(4)));

static __device__ __forceinline__ float b2f(unsigned short u) {
    union { unsigned int i; float f; } x;
    x.i = ((unsigned int)u) << 16;
    return x.f;
}
static __device__ __forceinline__ unsigned short f2b(float f) {
    union { __hip_bfloat16 h; unsigned short u; } x;
    x.h = __float2bfloat16(f);
    return x.u;
}

// ---- shared aggregation core: one halfwave aggregates one node's 8 columns/lane ----
static __device__ __forceinline__ float aggr_node(int off0, int deg, float adi,
                                                  const int* __restrict__ ssrc,
                                                  const float* __restrict__ sae,
                                                  const float* __restrict__ asrc,
                                                  const unsigned short* __restrict__ H,
                                                  int l, float* acc) {
    int sidx0 = 0, sidx1 = 0;
    float w0 = 0.f, w1 = 0.f;
    if (l < deg) {
        sidx0 = ssrc[off0 + l];
        float a = asrc[sidx0] + adi + sae[off0 + l];
        a = (a > 0.f) ? a : NEG_SLOPE_C * a;
        w0 = __expf(a);
    }
    if (32 + l < deg) {
        sidx1 = ssrc[off0 + 32 + l];
        float a = asrc[sidx1] + adi + sae[off0 + 32 + l];
        a = (a > 0.f) ? a : NEG_SLOPE_C * a;
        w1 = __expf(a);
    }
    float s = w0 + w1;
    for (int j = 64 + l; j < deg; j += 32) {  // cold tail
        int si = ssrc[off0 + j];
        float a = asrc[si] + adi + sae[off0 + j];
        a = (a > 0.f) ? a : NEG_SLOPE_C * a;
        s += __expf(a);
    }
#pragma unroll
    for (int o = 16; o > 0; o >>= 1) s += __shfl_xor(s, o, 32);
    float inv = 1.0f / (s + 1e-16f);

    int c8 = l * 8;
#pragma unroll
    for (int q = 0; q < 8; ++q) acc[q] = 0.f;

    auto fetch = [&](int j, int& si, float& wv) {
        if (j < 32) {
            si = __shfl(sidx0, j, 32);
            wv = __shfl(w0, j, 32);
        } else if (j < 64) {
            si = __shfl(sidx1, j - 32, 32);
            wv = __shfl(w1, j - 32, 32);
        } else {
            si = ssrc[off0 + j];
            float a = asrc[si] + adi + sae[off0 + j];
            a = (a > 0.f) ? a : NEG_SLOPE_C * a;
            wv = __expf(a);
        }
    };

    int j = 0;
    for (; j + 7 < deg; j += 8) {
        int ii[8];
        float uu[8];
#pragma unroll
        for (int q = 0; q < 8; ++q) fetch(j + q, ii[q], uu[q]);
        short8 h[8];
#pragma unroll
        for (int q = 0; q < 8; ++q) h[q] = *(const short8*)&H[(long)ii[q] * HID_C + c8];
#pragma unroll
        for (int t = 0; t < 8; ++t)
#pragma unroll
            for (int q = 0; q < 8; ++q) acc[q] += uu[t] * b2f((unsigned short)h[t][q]);
    }
    for (; j + 3 < deg; j += 4) {
        int ii[4];
        float uu[4];
#pragma unroll
        for (int q = 0; q < 4; ++q) fetch(j + q, ii[q], uu[q]);
        short8 h[4];
#pragma unroll
        for (int q = 0; q < 4; ++q) h[q] = *(const short8*)&H[(long)ii[q] * HID_C + c8];
#pragma unroll
        for (int t = 0; t < 4; ++t)
#pragma unroll
            for (int q = 0; q < 8; ++q) acc[q] += uu[t] * b2f((unsigned short)h[t][q]);
    }
    for (; j < deg; ++j) {
        int i0;
        float u0;
        fetch(j, i0, u0);
        short8 h0 = *(const short8*)&H[(long)i0 * HID_C + c8];
#pragma unroll
        for (int q = 0; q < 8; ++q) acc[q] += u0 * b2f((unsigned short)h0[q]);
    }
    return inv;
}

// ---------------- prep: W transposes + v12 (block 255) + zero deg ----------------
__global__ void k_prep(const float* __restrict__ W1, const float* __restrict__ W2,
                       unsigned short* __restrict__ W1t, unsigned short* __restrict__ W2t,
                       const float* __restrict__ We1, const float* __restrict__ atte1,
                       const float* __restrict__ We2, const float* __restrict__ atte2,
                       float* __restrict__ v, int* __restrict__ deg) {
    int tid = threadIdx.x;
    int i = blockIdx.x * blockDim.x + tid;
    if (i < N_NODES_C) deg[i] = 0;
    if (i < IN_DIM_C * HID_C) {
        int k = i >> 8, n = i & 255;
        W1t[n * IN_DIM_C + k] = f2b(W1[i]);
    }
    if (i < HID_C * HID_C) {
        int k = i >> 8, n = i & 255;
        W2t[n * HID_C + k] = f2b(W2[i]);
    }
    if (blockIdx.x == 255) {
        __shared__ float red[256];
        for (int layer = 0; layer < 2; ++layer) {
            const float* We = layer ? We2 : We1;
            const float* ae = layer ? atte2 : atte1;
            for (int k = 0; k < EDGE_DIM_C; ++k) {
                red[tid] = We[k * HID_C + tid] * ae[tid];
                __syncthreads();
                for (int s = 128; s > 0; s >>= 1) {
                    if (tid < s) red[tid] += red[tid + s];
                    __syncthreads();
                }
                if (tid == 0) v[layer * 8 + k] = red[0];
                __syncthreads();
            }
        }
    }
}

#define GEMM1_BLOCKS 782  // ceil(50000/64)

// ---------------- fused: GEMM1 (blocks < 782) + edge-pre (blocks >= 782) ----------
// edge-pre: histogram atomic's RETURN VALUE is the edge's rank within its dst.
__global__ __launch_bounds__(256) void k_pre_gemm1(
    const float* __restrict__ X, const unsigned short* __restrict__ Wt,
    unsigned short* __restrict__ H, const float* __restrict__ att_s,
    const float* __restrict__ att_d, float* __restrict__ asrc,
    float* __restrict__ adst,
    const int* __restrict__ dst, const float* __restrict__ eattr,
    const float* __restrict__ v, int* __restrict__ deg,
    float2* __restrict__ ae12, unsigned char* __restrict__ rank) {
    __shared__ unsigned short As[64 * 64];
    __shared__ unsigned short Bs[256 * 64];
    __shared__ float ds[4][64];
    __shared__ float dd[4][64];
    int tid = threadIdx.x;

    if (blockIdx.x >= GEMM1_BLOCKS) {
        int e = (blockIdx.x - GEMM1_BLOCKS) * 256 + tid;
        if (e < N_EDGES_C) {
            int r = atomicAdd(&deg[dst[e]], 1);
            rank[e] = (unsigned char)r;
            float a1 = 0.f, a2 = 0.f;
#pragma unroll
            for (int k = 0; k < EDGE_DIM_C; ++k) {
                float ea = eattr[e * EDGE_DIM_C + k];
                a1 += ea * v[k];
                a2 += ea * v[8 + k];
            }
            ae12[e] = make_float2(a1, a2);
        }
        return;
    }

    int w = tid >> 6, l = tid & 63;
    int lr = l & 15, lg = l >> 4;
    long mbase = (long)blockIdx.x * 64;

    float asv[4], adv[4];
#pragma unroll
    for (int ni = 0; ni < 4; ++ni) {
        int col = w * 64 + ni * 16 + lr;
        asv[ni] = att_s[col];
        adv[ni] = att_d[col];
    }

    f32x4 acc[4][4];
#pragma unroll
    for (int mi = 0; mi < 4; ++mi)
#pragma unroll
        for (int ni = 0; ni < 4; ++ni) acc[mi][ni] = (f32x4){0.f, 0.f, 0.f, 0.f};

    {
#pragma unroll
        for (int p = 0; p < 2; ++p) {
            int r = p * 32 + (tid >> 3);
            int c8 = tid & 7;
            long row = mbase + r;
            short8 val = {0, 0, 0, 0, 0, 0, 0, 0};
            if (row < N_NODES_C) {
                const f32x4* p4 = (const f32x4*)&X[row * IN_DIM_C + c8 * 8];
                f32x4 a0 = p4[0], a1 = p4[1];
#pragma unroll
                for (int q = 0; q < 4; ++q) val[q] = (short)f2b(a0[q]);
#pragma unroll
                for (int q = 0; q < 4; ++q) val[4 + q] = (short)f2b(a1[q]);
            }
            *(short8*)&As[r * 64 + ((c8 ^ (r & 7)) * 8)] = val;
        }
        int n = tid;
#pragma unroll
        for (int c8 = 0; c8 < 8; ++c8) {
            *(short8*)&Bs[n * 64 + ((c8 ^ (n & 7)) * 8)] =
                *(const short8*)&Wt[(long)n * IN_DIM_C + c8 * 8];
        }
        __syncthreads();
#pragma unroll
        for (int kk = 0; kk < 2; ++kk) {
            int cblk = kk * 4 + lg;
            short8 a[4], b[4];
#pragma unroll
            for (int mi = 0; mi < 4; ++mi) {
                int R = mi * 16 + lr;
                a[mi] = *(const short8*)&As[R * 64 + ((cblk ^ (R & 7)) * 8)];
            }
#pragma unroll
            for (int ni = 0; ni < 4; ++ni) {
                int Nr = w * 64 + ni * 16 + lr;
                b[ni] = *(const short8*)&Bs[Nr * 64 + ((cblk ^ (Nr & 7)) * 8)];
            }
#pragma unroll
            for (int mi = 0; mi < 4; ++mi)
#pragma unroll
                for (int ni = 0; ni < 4; ++ni)
                    acc[mi][ni] = __builtin_amdgcn_mfma_f32_16x16x32_bf16(a[mi], b[ni],
                                                                          acc[mi][ni], 0, 0, 0);
        }
        __syncthreads();
    }

#pragma unroll
    for (int mi = 0; mi < 4; ++mi) {
#pragma unroll
        for (int r = 0; r < 4; ++r) {
            int rowl = mi * 16 + lg * 4 + r;
            long row = mbase + rowl;
            float ps = 0.f, pd = 0.f;
#pragma unroll
            for (int ni = 0; ni < 4; ++ni) {
                float h = acc[mi][ni][r];
                ps += h * asv[ni];
                pd += h * adv[ni];
            }
#pragma unroll
            for (int o = 1; o < 16; o <<= 1) {
                ps += __shfl_xor(ps, o, 16);
                pd += __shfl_xor(pd, o, 16);
            }
            if (lr == 0) {
                ds[w][rowl] = ps;
                dd[w][rowl] = pd;
            }
            if (row < N_NODES_C) {
#pragma unroll
                for (int ni = 0; ni < 4; ++ni) {
                    H[row * HID_C + w * 64 + ni * 16 + lr] = f2b(acc[mi][ni][r]);
                }
            }
        }
    }
    __syncthreads();
    if (tid < 64) {
        long row = mbase + tid;
        if (row < N_NODES_C) {
            asrc[row] = ds[0][tid] + ds[1][tid] + ds[2][tid] + ds[3][tid];
            adst[row] = dd[0][tid] + dd[1][tid] + dd[2][tid] + dd[3][tid];
        }
    }
}

// ---------------- scan1: per-block exclusive scan + block sums ----------------
__global__ void k_scan1(const int* __restrict__ deg, int* __restrict__ offs,
                        int* __restrict__ bsum) {
    __shared__ int tmp[256];
    int b = blockIdx.x, tid = threadIdx.x;
    int i = b * 256 + tid;
    int v = (i < N_NODES_C) ? deg[i] : 0;
    tmp[tid] = v;
    __syncthreads();
    for (int d = 1; d < 256; d <<= 1) {
        int t = (tid >= d) ? tmp[tid - d] : 0;
        __syncthreads();
        tmp[tid] += t;
        __syncthreads();
    }
    if (i < N_NODES_C) offs[i] = tmp[tid] - v;
    if (tid == 255) bsum[b] = tmp[255];
}

// ---------------- scan3: add prefix of bsum (nb<=256 -> one reduction pass) --------
__global__ void k_scan3(int* __restrict__ offs, const int* __restrict__ bsum) {
    __shared__ int red[256];
    int b = blockIdx.x, tid = threadIdx.x;
    red[tid] = (tid < b) ? bsum[tid] : 0;
    __syncthreads();
    for (int s = 128; s > 0; s >>= 1) {
        if (tid < s) red[tid] += red[tid + s];
        __syncthreads();
    }
    int boff = red[0];
    int i = b * 256 + tid;
    if (i < N_NODES_C) offs[i] += boff;
    if (i == 0) offs[N_NODES_C] = N_EDGES_C;
}

// ---------------- perm build: NO atomics (offs + precomputed rank) ----------------
__global__ void k_perm(const int* __restrict__ dst, const unsigned char* __restrict__ rank,
                       const int* __restrict__ offs, int* __restrict__ perm) {
    int e = blockIdx.x * blockDim.x + threadIdx.x;
    if (e >= N_EDGES_C) return;
    int pos = offs[dst[e]] + (int)rank[e];
    perm[pos] = e;
}

// ---------------- CSR materialization: one random 8B read per edge ----------------
__global__ void k_gather(const int* __restrict__ perm, const int* __restrict__ src,
                         const float2* __restrict__ ae12,
                         int* __restrict__ ssrc, float* __restrict__ sae1,
                         float* __restrict__ sae2) {
    int p = blockIdx.x * blockDim.x + threadIdx.x;
    if (p >= N_EDGES_C) return;
    int e = perm[p];
    ssrc[p] = src[e];
    float2 a = ae12[e];
    sae1[p] = a.x;
    sae2[p] = a.y;
}

// ---------------- aggregation: halfwave per node; mode1 = bf16+relu, mode0 = f32 ------
__global__ __launch_bounds__(256) void k_aggr2(const int* __restrict__ offs,
                                               const int* __restrict__ ssrc,
                                               const float* __restrict__ sae,
                                               const float* __restrict__ asrc,
                                               const float* __restrict__ adst,
                                               const unsigned short* __restrict__ H,
                                               const float* __restrict__ bias,
                                               void* __restrict__ outp, int mode) {
    int tid = threadIdx.x;
    int hw = tid >> 5;
    int l = tid & 31;
    int node = blockIdx.x * 8 + hw;
    int off0 = offs[node];
    int deg = offs[node + 1] - off0;
    float adi = adst[node];
    float acc[8];
    float inv = aggr_node(off0, deg, adi, ssrc, sae, asrc, H, l, acc);
    int c8 = l * 8;
    const f32x4* b4 = (const f32x4*)&bias[c8];
    f32x4 bv0 = b4[0], bv1 = b4[1];
    if (mode == 1) {
        unsigned short* o16 = (unsigned short*)outp;
        short8 r;
#pragma unroll
        for (int q = 0; q < 4; ++q)
            r[q] = (short)f2b(fmaxf(acc[q] * inv + bv0[q], 0.f));
#pragma unroll
        for (int q = 0; q < 4; ++q)
            r[4 + q] = (short)f2b(fmaxf(acc[4 + q] * inv + bv1[q], 0.f));
        *(short8*)&o16[(long)node * HID_C + c8] = r;
    } else {
        float* o32 = (float*)outp;
        f32x4 r0, r1;
#pragma unroll
        for (int q = 0; q < 4; ++q) r0[q] = acc[q] * inv + bv0[q];
#pragma unroll
        for (int q = 0; q < 4; ++q) r1[q] = acc[4 + q] * inv + bv1[q];
        *(f32x4*)&o32[(long)node * HID_C + c8] = r0;
        *(f32x4*)&o32[(long)node * HID_C + c8 + 4] = r1;
    }
}

// ---------------- GEMM2: A staged g1->LDS (swizzled), B direct from L2, fused dots ----
__global__ __launch_bounds__(256) void k_gemm2(
    const unsigned short* __restrict__ G, const unsigned short* __restrict__ Wt,
    unsigned short* __restrict__ H2, const float* __restrict__ att_s,
    const float* __restrict__ att_d, float* __restrict__ asrc2,
    float* __restrict__ adst2) {
    __shared__ unsigned short As[64 * 256];  // 32 KB, swizzled per 64-elem chunk
    __shared__ float ds[4][64];
    __shared__ float dd[4][64];
    int tid = threadIdx.x;
    long mbase = (long)blockIdx.x * 64;

    int hw = tid >> 5, l = tid & 31;
#pragma unroll
    for (int p = 0; p < 8; ++p) {
        int rowl = p * 8 + hw;
        long row = mbase + rowl;
        short8 val = {0, 0, 0, 0, 0, 0, 0, 0};
        if (row < N_NODES_C) val = *(const short8*)&G[row * HID_C + l * 8];
        *(short8*)&As[rowl * 256 + (l >> 3) * 64 + (((l & 7) ^ (rowl & 7)) * 8)] = val;
    }
    __syncthreads();

    int w = tid >> 6, l64 = tid & 63;
    int lr = l64 & 15, lg = l64 >> 4;

    float asv[4], adv[4];
#pragma unroll
    for (int ni = 0; ni < 4; ++ni) {
        int col = w * 64 + ni * 16 + lr;
        asv[ni] = att_s[col];
        adv[ni] = att_d[col];
    }

    f32x4 acc[4][4];
#pragma unroll
    for (int mi = 0; mi < 4; ++mi)
#pragma unroll
        for (int ni = 0; ni < 4; ++ni) acc[mi][ni] = (f32x4){0.f, 0.f, 0.f, 0.f};

#pragma unroll
    for (int k0 = 0; k0 < HID_C; k0 += 64) {
#pragma unroll
        for (int kk = 0; kk < 2; ++kk) {
            int cblk = kk * 4 + lg;
            short8 a[4], b[4];
#pragma unroll
            for (int mi = 0; mi < 4; ++mi) {
                int R = mi * 16 + lr;
                a[mi] = *(const short8*)&As[R * 256 + k0 + ((cblk ^ (R & 7)) * 8)];
            }
#pragma unroll
            for (int ni = 0; ni < 4; ++ni) {
                int Nr = w * 64 + ni * 16 + lr;
                b[ni] = *(const short8*)&Wt[(long)Nr * HID_C + k0 + cblk * 8];
            }
#pragma unroll
            for (int mi = 0; mi < 4; ++mi)
#pragma unroll
                for (int ni = 0; ni < 4; ++ni)
                    acc[mi][ni] = __builtin_amdgcn_mfma_f32_16x16x32_bf16(a[mi], b[ni],
                                                                          acc[mi][ni], 0, 0, 0);
        }
    }

#pragma unroll
    for (int mi = 0; mi < 4; ++mi) {
#pragma unroll
        for (int r = 0; r < 4; ++r) {
            int rowl = mi * 16 + lg * 4 + r;
            long row = mbase + rowl;
            float ps = 0.f, pd = 0.f;
#pragma unroll
            for (int ni = 0; ni < 4; ++ni) {
                float h = acc[mi][ni][r];
                ps += h * asv[ni];
                pd += h * adv[ni];
            }
#pragma unroll
            for (int o = 1; o < 16; o <<= 1) {
                ps += __shfl_xor(ps, o, 16);
                pd += __shfl_xor(pd, o, 16);
            }
            if (lr == 0) {
                ds[w][rowl] = ps;
                dd[w][rowl] = pd;
            }
            if (row < N_NODES_C) {
#pragma unroll
                for (int ni = 0; ni < 4; ++ni) {
                    H2[row * HID_C + w * 64 + ni * 16 + lr] = f2b(acc[mi][ni][r]);
                }
            }
        }
    }
    __syncthreads();
    if (tid < 64) {
        long row = mbase + tid;
        if (row < N_NODES_C) {
            asrc2[row] = ds[0][tid] + ds[1][tid] + ds[2][tid] + ds[3][tid];
            adst2[row] = dd[0][tid] + dd[1][tid] + dd[2][tid] + dd[3][tid];
        }
    }
}

extern "C" void kernel_launch(void* const* d_in, const int* in_sizes, int n_in,
                              void* d_out, int out_size, void* d_ws, size_t ws_size,
                              hipStream_t stream) {
    const float* x     = (const float*)d_in[0];
    const int*   ei    = (const int*)d_in[1];     // [2, E]: row0=src, row1=dst
    const float* eattr = (const float*)d_in[2];
    const float* W1    = (const float*)d_in[3];
    const float* atts1 = (const float*)d_in[4];
    const float* attd1 = (const float*)d_in[5];
    const float* We1   = (const float*)d_in[6];
    const float* atte1 = (const float*)d_in[7];
    const float* b1    = (const float*)d_in[8];
    const float* W2    = (const float*)d_in[9];
    const float* atts2 = (const float*)d_in[10];
    const float* attd2 = (const float*)d_in[11];
    const float* We2   = (const float*)d_in[12];
    const float* atte2 = (const float*)d_in[13];
    const float* b2    = (const float*)d_in[14];
    float* out = (float*)d_out;

    char* ws = (char*)d_ws;
    size_t off = 0;
    auto alloc = [&](size_t bytes) -> void* {
        void* p = ws + off;
        off = (off + bytes + 255) & ~(size_t)255;
        return p;
    };
    int*    deg   = (int*)alloc((size_t)N_NODES_C * 4);
    int*    offs  = (int*)alloc(((size_t)N_NODES_C + 1) * 4);
    int*    perm  = (int*)alloc((size_t)N_EDGES_C * 4);
    int*    ssrc  = (int*)alloc((size_t)N_EDGES_C * 4);
    float2* ae12  = (float2*)alloc((size_t)N_EDGES_C * 8);
    unsigned char* rank = (unsigned char*)alloc((size_t)N_EDGES_C);
    float*  sae1  = (float*)alloc((size_t)N_EDGES_C * 4);
    float*  sae2  = (float*)alloc((size_t)N_EDGES_C * 4);
    float*  asrc  = (float*)alloc((size_t)N_NODES_C * 4);
    float*  adst  = (float*)alloc((size_t)N_NODES_C * 4);
    float*  asrc2 = (float*)alloc((size_t)N_NODES_C * 4);
    float*  adst2 = (float*)alloc((size_t)N_NODES_C * 4);
    float*  v     = (float*)alloc(64);
    int*    bsum  = (int*)alloc(256 * 4);
    unsigned short* W1t = (unsigned short*)alloc((size_t)HID_C * IN_DIM_C * 2);
    unsigned short* W2t = (unsigned short*)alloc((size_t)HID_C * HID_C * 2);
    unsigned short* h1  = (unsigned short*)alloc((size_t)N_NODES_C * HID_C * 2);
    unsigned short* g1  = (unsigned short*)alloc((size_t)N_NODES_C * HID_C * 2);
    unsigned short* h2  = h1;  // layer-2 features overwrite h1 (h1 dead after aggr1)

    const int* src = ei;
    const int* dst = ei + N_EDGES_C;
    int nb = (N_NODES_C + 255) / 256;  // 196
    int pre_blocks = (N_EDGES_C + 255) / 256;  // 3125
    int gemm_grid = (N_NODES_C + 63) / 64;     // 782 == GEMM1_BLOCKS

    k_prep<<<256, 256, 0, stream>>>(W1, W2, W1t, W2t, We1, atte1, We2, atte2, v, deg);
    k_pre_gemm1<<<GEMM1_BLOCKS + pre_blocks, 256, 0, stream>>>(
        x, W1t, h1, atts1, attd1, asrc, adst, dst, eattr, v, deg, ae12, rank);
    k_scan1<<<nb, 256, 0, stream>>>(deg, offs, bsum);
    k_scan3<<<nb, 256, 0, stream>>>(offs, bsum);
    k_perm<<<pre_blocks, 256, 0, stream>>>(dst, rank, offs, perm);
    k_gather<<<pre_blocks, 256, 0, stream>>>(perm, src, ae12, ssrc, sae1, sae2);

    // layer 1 aggregation -> bf16 g1
    k_aggr2<<<N_NODES_C / 8, 256, 0, stream>>>(offs, ssrc, sae1, asrc, adst, h1, b1, g1, 1);
    // layer 2 GEMM (g1 -> h2) + fused dots
    k_gemm2<<<gemm_grid, 256, 0, stream>>>(g1, W2t, h2, atts2, attd2, asrc2, adst2);
    // layer 2 aggregation -> f32 out
    k_aggr2<<<N_NODES_C / 8, 256, 0, stream>>>(offs, ssrc, sae2, asrc2, adst2, h2, b2, out, 0);
}